// Round 1
// baseline (2760.828 us; speedup 1.0000x reference)
//
#include <hip/hip_runtime.h>
#include <math.h>

#define N_NODES 1024
#define T_STEPS 32
#define F_DIM   128
#define H_HEADS 4
#define D_HEAD  32
#define DEG     32
#define HID     512
#define OUT_DIM 64
#define TF      (T_STEPS * F_DIM)   // 4096
#define NT      (N_NODES * T_STEPS) // 32768
#define F3      (3 * F_DIM)         // 384

// ---------------------------------------------------------------- utilities
__global__ void zero_kernel(float* p, int n) {
    int i = blockIdx.x * 256 + threadIdx.x;
    if (i < n) p[i] = 0.f;
}

// transpose W_hh [384,128] -> W_hhT [128,384]
__global__ void transpose_whh(const float* __restrict__ W, float* __restrict__ WT) {
    int idx = blockIdx.x * 256 + threadIdx.x;
    if (idx < F3 * F_DIM) {
        int j = idx / F_DIM;   // 0..383
        int k = idx % F_DIM;   // 0..127
        WT[k * F3 + j] = W[idx];
    }
}

// ---------------------------------------------------------------- SpMM (wide): Y[n, 0..4096) = sum_e vals * X[cols[e], :]
__global__ void spmm_wide(const int* __restrict__ cols, const float* __restrict__ vals,
                          const float* __restrict__ X, float* __restrict__ Y) {
    int n = blockIdx.y;
    int c = blockIdx.x * 256 + threadIdx.x;
    const int*   ce = cols + n * DEG;
    const float* ve = vals + n * DEG;
    float acc = 0.f;
#pragma unroll
    for (int e = 0; e < DEG; ++e) acc += ve[e] * X[ce[e] * TF + c];
    Y[n * TF + c] = acc;
}

// ---------------------------------------------------------------- fused SpMM(F) + @W_gcn + relu : h_out = relu((A@g) @ Wg)
__global__ void spmm_gcn(const int* __restrict__ cols, const float* __restrict__ vals,
                         const float* __restrict__ g_in, const float* __restrict__ Wg,
                         float* __restrict__ h_out) {
    __shared__ float sp[F_DIM];
    int n = blockIdx.x, tid = threadIdx.x;   // 128 threads
    const int*   ce = cols + n * DEG;
    const float* ve = vals + n * DEG;
    float acc = 0.f;
#pragma unroll
    for (int e = 0; e < DEG; ++e) acc += ve[e] * g_in[ce[e] * F_DIM + tid];
    sp[tid] = acc;
    __syncthreads();
    float o = 0.f;
    for (int k = 0; k < F_DIM; ++k) o += sp[k] * Wg[k * F_DIM + tid];
    h_out[n * F_DIM + tid] = fmaxf(o, 0.f);
}

// ---------------------------------------------------------------- GRU step: g = GRUCell(x_t, h); Hm[:,t,:] = g + pe
// GI holds x@W_ih^T + b_ih for all (n,t).  16 rows per block, 256 threads.
__global__ __launch_bounds__(256) void gru_step(const float* __restrict__ GI,
                                                const float* __restrict__ h_in,
                                                const float* __restrict__ WhhT,
                                                const float* __restrict__ b_hh,
                                                float* __restrict__ g_out,
                                                float* __restrict__ Hm, int t) {
    __shared__ float hs[16][F_DIM];
    int tid  = threadIdx.x;
    int row0 = blockIdx.x * 16;
    for (int idx = tid; idx < 16 * F_DIM; idx += 256) {
        int j = idx >> 7, f2 = idx & 127;
        hs[j][f2] = h_in[(row0 + j) * F_DIM + f2];
    }
    __syncthreads();
    int f  = tid & 127;
    int rg = tid >> 7;   // 0 or 1
    float hr[8], hz[8], hn[8];
#pragma unroll
    for (int i = 0; i < 8; ++i) { hr[i] = 0.f; hz[i] = 0.f; hn[i] = 0.f; }
    for (int k = 0; k < F_DIM; ++k) {
        float wr = WhhT[k * F3 + f];
        float wz = WhhT[k * F3 + 128 + f];
        float wn = WhhT[k * F3 + 256 + f];
#pragma unroll
        for (int i = 0; i < 8; ++i) {
            float hv = hs[rg * 8 + i][k];
            hr[i] += hv * wr; hz[i] += hv * wz; hn[i] += hv * wn;
        }
    }
    float br = b_hh[f], bz = b_hh[128 + f], bn = b_hh[256 + f];
#pragma unroll
    for (int i = 0; i < 8; ++i) {
        int r = rg * 8 + i;
        int n = row0 + r;
        int gib = (n * T_STEPS + t) * F3;
        float ir  = GI[gib + f];
        float iz  = GI[gib + 128 + f];
        float inn = GI[gib + 256 + f];
        float rr = 1.f / (1.f + expf(-(ir + hr[i] + br)));
        float zz = 1.f / (1.f + expf(-(iz + hz[i] + bz)));
        float nn = tanhf(inn + rr * (hn[i] + bn));
        float g  = (1.f - zz) * nn + zz * hs[r][f];
        g_out[n * F_DIM + f] = g;
        // positional encoding: pe[n,t] constant over features
        float inv = expf(-(float)n * (9.210340371976184f / 64.0f)); // 10000^(-2n/F)
        float ang = (float)t * inv;
        float pe  = ((t & 1) == 0) ? sinf(ang) : cosf(ang);
        Hm[(n * T_STEPS + t) * F_DIM + f] = g + pe;
    }
}

// ---------------------------------------------------------------- qkv [N,T,3F] -> Qt/Kt/Vt [T*H, N, D] (q scaled)
__global__ void qkv_transpose(const float* __restrict__ qkv, float* __restrict__ Qt,
                              float* __restrict__ Kt, float* __restrict__ Vt) {
    int idx = blockIdx.x * 256 + threadIdx.x;   // over N*T*F
    if (idx >= N_NODES * TF) return;
    int n = idx / TF;
    int rem = idx % TF;
    int t = rem / F_DIM;
    int f = rem % F_DIM;
    int hh = f >> 5, d = f & 31;
    int src = (n * T_STEPS + t) * F3;
    int dst = ((t * H_HEADS + hh) * N_NODES + n) * D_HEAD + d;
    Qt[dst] = qkv[src + f] * 0.17677669529663687f;  // 1/sqrt(32)
    Kt[dst] = qkv[src + 128 + f];
    Vt[dst] = qkv[src + 256 + f];
}

// ---------------------------------------------------------------- flash attention per (t,h), 32 query rows per block
__global__ __launch_bounds__(256) void attn_kernel(const float* __restrict__ Qt,
                                                   const float* __restrict__ Kt,
                                                   const float* __restrict__ Vt,
                                                   float* __restrict__ ctx) {
    int th = blockIdx.x;            // t*H + h
    int t = th >> 2, hh = th & 3;
    int row0 = blockIdx.y * 32;
    int tid = threadIdx.x;
    __shared__ float qs[32][33], Ks[32][33], Vs[32][33], st[32][33];
    const float* Qb = Qt + th * (N_NODES * D_HEAD);
    const float* Kb = Kt + th * (N_NODES * D_HEAD);
    const float* Vb = Vt + th * (N_NODES * D_HEAD);
    for (int idx = tid; idx < 1024; idx += 256) {
        int r = idx >> 5, d = idx & 31;
        qs[r][d] = Qb[(row0 + r) * D_HEAD + d];
    }
    int d  = tid & 31;
    int rq = tid >> 5;   // 0..7
    int ra = tid >> 3;   // phase-A row 0..31
    int mb = tid & 7;
    float cacc[4] = {0.f, 0.f, 0.f, 0.f};
    float lrun[4] = {0.f, 0.f, 0.f, 0.f};
    float mrun[4] = {-1e30f, -1e30f, -1e30f, -1e30f};
    for (int mt = 0; mt < 32; ++mt) {
        int m0 = mt * 32;
        __syncthreads();
        for (int idx = tid; idx < 1024; idx += 256) {
            int r = idx >> 5, dd = idx & 31;
            Ks[r][dd] = Kb[(m0 + r) * D_HEAD + dd];
            Vs[r][dd] = Vb[(m0 + r) * D_HEAD + dd];
        }
        __syncthreads();
#pragma unroll
        for (int j = 0; j < 4; ++j) {
            int m = mb + j * 8;
            float acc = 0.f;
#pragma unroll
            for (int dd = 0; dd < 32; ++dd) acc += qs[ra][dd] * Ks[m][dd];
            st[ra][m] = acc;
        }
        __syncthreads();
#pragma unroll
        for (int i = 0; i < 4; ++i) {
            int r = rq + 8 * i;
            float tmax = -1e30f;
#pragma unroll
            for (int m = 0; m < 32; ++m) tmax = fmaxf(tmax, st[r][m]);
            float mnew = fmaxf(mrun[i], tmax);
            float al = __expf(mrun[i] - mnew);
            lrun[i] *= al;
            cacc[i] *= al;
            float ls = 0.f;
#pragma unroll
            for (int m = 0; m < 32; ++m) {
                float p = __expf(st[r][m] - mnew);
                ls += p;
                cacc[i] += p * Vs[m][d];
            }
            lrun[i] += ls;
            mrun[i] = mnew;
        }
    }
#pragma unroll
    for (int i = 0; i < 4; ++i) {
        int n = row0 + rq + 8 * i;
        ctx[(n * T_STEPS + t) * F_DIM + hh * D_HEAD + d] = cacc[i] / lrun[i];
    }
}

// ---------------------------------------------------------------- LayerNorm over F=128, optional residual
__global__ void ln_kernel(const float* __restrict__ a, const float* __restrict__ resid,
                          const float* __restrict__ gamma, const float* __restrict__ beta,
                          float* __restrict__ out) {
    int row = blockIdx.x;
    int tid = threadIdx.x;    // 64 threads, 2 elements each
    int base = row * F_DIM;
    float x0 = a[base + tid], x1 = a[base + 64 + tid];
    if (resid) { x0 += resid[base + tid]; x1 += resid[base + 64 + tid]; }
    float s = x0 + x1;
#pragma unroll
    for (int o = 32; o > 0; o >>= 1) s += __shfl_xor(s, o);
    float mu = s * (1.f / 128.f);
    float d0 = x0 - mu, d1 = x1 - mu;
    float v = d0 * d0 + d1 * d1;
#pragma unroll
    for (int o = 32; o > 0; o >>= 1) v += __shfl_xor(v, o);
    float inv = rsqrtf(v * (1.f / 128.f) + 1e-5f);
    out[base + tid]      = d0 * inv * gamma[tid] + beta[tid];
    out[base + 64 + tid] = d1 * inv * gamma[64 + tid] + beta[64 + tid];
}

// ---------------------------------------------------------------- tiled fp32 GEMM: C[M,P] = A[M,K] @ B (+bias, relu)
// TB ? B is [P,K] (use B^T) : B is [K,P]
template <bool TB, bool RELU>
__global__ __launch_bounds__(256) void gemm_kernel(const float* __restrict__ A,
                                                   const float* __restrict__ B,
                                                   const float* __restrict__ bias,
                                                   float* __restrict__ C,
                                                   int M, int K, int P) {
    __shared__ float As[16][65];
    __shared__ float Bs[16][65];
    int tid = threadIdx.x;
    int tx = tid & 15, ty = tid >> 4;
    int p0 = blockIdx.x * 64, row0 = blockIdx.y * 64;
    float acc[4][4] = {};
    for (int k0 = 0; k0 < K; k0 += 16) {
        {
            int m = tid & 63, kb = (tid >> 6) * 4;
            const float4 f4 = *(const float4*)(A + (size_t)(row0 + m) * K + k0 + kb);
            As[kb + 0][m] = f4.x; As[kb + 1][m] = f4.y;
            As[kb + 2][m] = f4.z; As[kb + 3][m] = f4.w;
        }
        if (TB) {
            int p = tid >> 2, kb = (tid & 3) * 4;
            const float4 f4 = *(const float4*)(B + (size_t)(p0 + p) * K + k0 + kb);
            Bs[kb + 0][p] = f4.x; Bs[kb + 1][p] = f4.y;
            Bs[kb + 2][p] = f4.z; Bs[kb + 3][p] = f4.w;
        } else {
            int p = tid & 63, kb = (tid >> 6) * 4;
#pragma unroll
            for (int j = 0; j < 4; ++j) Bs[kb + j][p] = B[(size_t)(k0 + kb + j) * P + p0 + p];
        }
        __syncthreads();
#pragma unroll
        for (int k = 0; k < 16; ++k) {
            float av[4], bv[4];
#pragma unroll
            for (int i = 0; i < 4; ++i) av[i] = As[k][ty * 4 + i];
#pragma unroll
            for (int j = 0; j < 4; ++j) bv[j] = Bs[k][tx * 4 + j];
#pragma unroll
            for (int i = 0; i < 4; ++i)
#pragma unroll
                for (int j = 0; j < 4; ++j) acc[i][j] += av[i] * bv[j];
        }
        __syncthreads();
    }
#pragma unroll
    for (int i = 0; i < 4; ++i) {
        int row = row0 + ty * 4 + i;
#pragma unroll
        for (int j = 0; j < 4; ++j) {
            int col = p0 + tx * 4 + j;
            float v = acc[i][j] + (bias ? bias[col] : 0.f);
            if (RELU) v = fmaxf(v, 0.f);
            C[(size_t)row * P + col] = v;
        }
    }
}

// ---------------------------------------------------------------- launch
extern "C" void kernel_launch(void* const* d_in, const int* in_sizes, int n_in,
                              void* d_out, int out_size, void* d_ws, size_t ws_size,
                              hipStream_t stream) {
    const int*   A_cols     = (const int*)d_in[1];
    const float* A_vals     = (const float*)d_in[2];
    const float* X          = (const float*)d_in[3];
    const float* W_gcn      = (const float*)d_in[4];
    const float* W_ih       = (const float*)d_in[5];
    const float* W_hh       = (const float*)d_in[6];
    const float* b_ih       = (const float*)d_in[7];
    const float* b_hh       = (const float*)d_in[8];
    const float* in_proj_w  = (const float*)d_in[9];
    const float* in_proj_b  = (const float*)d_in[10];
    const float* out_proj_w = (const float*)d_in[11];
    const float* out_proj_b = (const float*)d_in[12];
    const float* ln1_g = (const float*)d_in[13];
    const float* ln1_b = (const float*)d_in[14];
    const float* ln2_g = (const float*)d_in[15];
    const float* ln2_b = (const float*)d_in[16];
    const float* lnf_g = (const float*)d_in[17];
    const float* lnf_b = (const float*)d_in[18];
    const float* ff1_w = (const float*)d_in[19];
    const float* ff1_b = (const float*)d_in[20];
    const float* ff2_w = (const float*)d_in[21];
    const float* ff2_b = (const float*)d_in[22];
    const float* fc1_w = (const float*)d_in[23];
    const float* fc1_b = (const float*)d_in[24];
    const float* fc2_w = (const float*)d_in[25];
    const float* fc2_b = (const float*)d_in[26];
    const float* fc3_w = (const float*)d_in[27];
    const float* fc3_b = (const float*)d_in[28];
    float* out = (float*)d_out;
    float* ws  = (float*)d_ws;

    // workspace layout (floats); total ~156 MB
    const size_t o_Hm = 0;                       // [N,T,F]  4,194,304
    const size_t o_A  = o_Hm + 4194304;          // X_s -> ctx -> x1 -> enc
    const size_t o_B  = o_A + 4194304;           // X_tilde -> attn_out -> ff_out
    const size_t o_C  = o_B + 4194304;           // GI -> qkv -> ff_hid(16.8M, spills into o_D)
    const size_t o_D  = o_C + 12582912;          // Qt,Kt,Vt (3 x 4,194,304)
    const size_t o_WT = o_D + 12582912;          // W_hhT 49,152
    const size_t o_h  = o_WT + 49152;            // h 131,072
    const size_t o_g  = o_h + 131072;            // g 131,072
    const size_t o_h1 = o_g + 131072;            // 524,288
    const size_t o_h2 = o_h1 + 524288;           // 524,288

    float* Hm   = ws + o_Hm;
    float* bufA = ws + o_A;
    float* bufB = ws + o_B;
    float* bufC = ws + o_C;
    float* Qt   = ws + o_D;
    float* Kt   = Qt + 4194304;
    float* Vt   = Kt + 4194304;
    float* WhhT = ws + o_WT;
    float* hbuf = ws + o_h;
    float* gbuf = ws + o_g;
    float* h1   = ws + o_h1;
    float* h2   = ws + o_h2;

    // 1. X_s = A_hat @ X  [N, T*F] -> bufA
    spmm_wide<<<dim3(16, 1024), 256, 0, stream>>>(A_cols, A_vals, X, bufA);
    // 2. X_tilde = relu(X_s @ W_gcn) -> bufB  (view [NT,F])
    gemm_kernel<false, true><<<dim3(2, 512), 256, 0, stream>>>(bufA, W_gcn, nullptr, bufB, NT, F_DIM, F_DIM);
    // 3. GI = X_tilde @ W_ih^T + b_ih -> bufC [NT, 384]  (hoisted out of the scan)
    gemm_kernel<true, false><<<dim3(6, 512), 256, 0, stream>>>(bufB, W_ih, b_ih, bufC, NT, F_DIM, F3);
    // 4. W_hh transpose (once)
    transpose_whh<<<192, 256, 0, stream>>>(W_hh, WhhT);
    // 5. h0 = 0
    zero_kernel<<<512, 256, 0, stream>>>(hbuf, 131072);
    // 6. sequential scan
    for (int t = 0; t < T_STEPS; ++t) {
        gru_step<<<64, 256, 0, stream>>>(bufC, hbuf, WhhT, b_hh, gbuf, Hm, t);
        spmm_gcn<<<1024, 128, 0, stream>>>(A_cols, A_vals, gbuf, W_gcn, hbuf);
    }
    // 7. qkv = Hm @ in_proj_w^T + b -> bufC [NT, 384]
    gemm_kernel<true, false><<<dim3(6, 512), 256, 0, stream>>>(Hm, in_proj_w, in_proj_b, bufC, NT, F_DIM, F3);
    // 8. transpose to [T*H, N, D] (+ scale q)
    qkv_transpose<<<16384, 256, 0, stream>>>(bufC, Qt, Kt, Vt);
    // 9. attention -> ctx (bufA)
    attn_kernel<<<dim3(128, 32), 256, 0, stream>>>(Qt, Kt, Vt, bufA);
    // 10. attn_out = ctx @ out_proj_w^T + b -> bufB
    gemm_kernel<true, false><<<dim3(2, 512), 256, 0, stream>>>(bufA, out_proj_w, out_proj_b, bufB, NT, F_DIM, F_DIM);
    // 11. x1 = LN(Hm + attn_out) -> bufA
    ln_kernel<<<NT, 64, 0, stream>>>(Hm, bufB, ln1_g, ln1_b, bufA);
    // 12. ff_hid = relu(x1 @ ff1_w^T + b) -> bufC (spans into Qt region, both dead)
    gemm_kernel<true, true><<<dim3(8, 512), 256, 0, stream>>>(bufA, ff1_w, ff1_b, bufC, NT, F_DIM, HID);
    // 13. ff_out = ff_hid @ ff2_w^T + b -> bufB
    gemm_kernel<true, false><<<dim3(2, 512), 256, 0, stream>>>(bufC, ff2_w, ff2_b, bufB, NT, HID, F_DIM);
    // 14. x2 = LN(x1 + ff_out) -> Hm
    ln_kernel<<<NT, 64, 0, stream>>>(bufA, bufB, ln2_g, ln2_b, Hm);
    // 15. enc = LN(x2) -> bufA
    ln_kernel<<<NT, 64, 0, stream>>>(Hm, nullptr, lnf_g, lnf_b, bufA);
    // 16. h1 = relu(enc_flat @ fc1_w^T + b)  [1024, 4096] -> [1024, 512]
    gemm_kernel<true, true><<<dim3(8, 16), 256, 0, stream>>>(bufA, fc1_w, fc1_b, h1, N_NODES, TF, HID);
    // 17. h2 = relu(h1 @ fc2_w^T + b)
    gemm_kernel<true, true><<<dim3(8, 16), 256, 0, stream>>>(h1, fc2_w, fc2_b, h2, N_NODES, HID, HID);
    // 18. out = h2 @ fc3_w^T + b  [1024, 64]
    gemm_kernel<true, false><<<dim3(1, 16), 256, 0, stream>>>(h2, fc3_w, fc3_b, out, N_NODES, HID, OUT_DIM);
}

// Round 2
// 1735.591 us; speedup vs baseline: 1.5907x; 1.5907x over previous
//
#include <hip/hip_runtime.h>
#include <math.h>

#define N_NODES 1024
#define T_STEPS 32
#define F_DIM   128
#define H_HEADS 4
#define D_HEAD  32
#define DEG     32
#define HID     512
#define OUT_DIM 64
#define TF      (T_STEPS * F_DIM)   // 4096
#define NT      (N_NODES * T_STEPS) // 32768
#define F3      (3 * F_DIM)         // 384

typedef __attribute__((ext_vector_type(8))) __bf16 bf16x8;
typedef __attribute__((ext_vector_type(4))) float  f32x4;

// float -> bf16 bits, round-to-nearest-even
__device__ __forceinline__ short f2bf(float x) {
    union { float f; unsigned u; } v; v.f = x;
    unsigned r = (v.u + 0x7FFFu + ((v.u >> 16) & 1u)) >> 16;
    return (short)r;
}

// ---------------------------------------------------------------- utilities
__global__ void zero_kernel(float* p, int n) {
    int i = blockIdx.x * 256 + threadIdx.x;
    if (i < n) p[i] = 0.f;
}

// transpose W_hh [384,128] -> W_hhT [128,384]
__global__ void transpose_whh(const float* __restrict__ W, float* __restrict__ WT) {
    int idx = blockIdx.x * 256 + threadIdx.x;
    if (idx < F3 * F_DIM) {
        int j = idx / F_DIM;   // 0..383
        int k = idx % F_DIM;   // 0..127
        WT[k * F3 + j] = W[idx];
    }
}

// ---------------------------------------------------------------- SpMM (wide): Y[n, 0..4096) = sum_e vals * X[cols[e], :]
__global__ void spmm_wide(const int* __restrict__ cols, const float* __restrict__ vals,
                          const float* __restrict__ X, float* __restrict__ Y) {
    int n = blockIdx.y;
    int c = blockIdx.x * 256 + threadIdx.x;
    const int*   ce = cols + n * DEG;
    const float* ve = vals + n * DEG;
    float acc = 0.f;
#pragma unroll
    for (int e = 0; e < DEG; ++e) acc += ve[e] * X[ce[e] * TF + c];
    Y[n * TF + c] = acc;
}

// ---------------------------------------------------------------- fused SpMM(F) + @W_gcn + relu : h_out = relu((A@g) @ Wg)
__global__ void spmm_gcn(const int* __restrict__ cols, const float* __restrict__ vals,
                         const float* __restrict__ g_in, const float* __restrict__ Wg,
                         float* __restrict__ h_out) {
    __shared__ float sp[F_DIM];
    int n = blockIdx.x, tid = threadIdx.x;   // 128 threads
    const int*   ce = cols + n * DEG;
    const float* ve = vals + n * DEG;
    float acc = 0.f;
#pragma unroll
    for (int e = 0; e < DEG; ++e) acc += ve[e] * g_in[ce[e] * F_DIM + tid];
    sp[tid] = acc;
    __syncthreads();
    float o = 0.f;
    for (int k = 0; k < F_DIM; ++k) o += sp[k] * Wg[k * F_DIM + tid];
    h_out[n * F_DIM + tid] = fmaxf(o, 0.f);
}

// ---------------------------------------------------------------- GRU step: g = GRUCell(x_t, h); Hm[:,t,:] = g + pe
__global__ __launch_bounds__(256) void gru_step(const float* __restrict__ GI,
                                                const float* __restrict__ h_in,
                                                const float* __restrict__ WhhT,
                                                const float* __restrict__ b_hh,
                                                float* __restrict__ g_out,
                                                float* __restrict__ Hm, int t) {
    __shared__ float hs[16][F_DIM];
    int tid  = threadIdx.x;
    int row0 = blockIdx.x * 16;
    for (int idx = tid; idx < 16 * F_DIM; idx += 256) {
        int j = idx >> 7, f2 = idx & 127;
        hs[j][f2] = h_in[(row0 + j) * F_DIM + f2];
    }
    __syncthreads();
    int f  = tid & 127;
    int rg = tid >> 7;   // 0 or 1
    float hr[8], hz[8], hn[8];
#pragma unroll
    for (int i = 0; i < 8; ++i) { hr[i] = 0.f; hz[i] = 0.f; hn[i] = 0.f; }
    for (int k = 0; k < F_DIM; ++k) {
        float wr = WhhT[k * F3 + f];
        float wz = WhhT[k * F3 + 128 + f];
        float wn = WhhT[k * F3 + 256 + f];
#pragma unroll
        for (int i = 0; i < 8; ++i) {
            float hv = hs[rg * 8 + i][k];
            hr[i] += hv * wr; hz[i] += hv * wz; hn[i] += hv * wn;
        }
    }
    float br = b_hh[f], bz = b_hh[128 + f], bn = b_hh[256 + f];
#pragma unroll
    for (int i = 0; i < 8; ++i) {
        int r = rg * 8 + i;
        int n = row0 + r;
        int gib = (n * T_STEPS + t) * F3;
        float ir  = GI[gib + f];
        float iz  = GI[gib + 128 + f];
        float inn = GI[gib + 256 + f];
        float rr = 1.f / (1.f + expf(-(ir + hr[i] + br)));
        float zz = 1.f / (1.f + expf(-(iz + hz[i] + bz)));
        float nn = tanhf(inn + rr * (hn[i] + bn));
        float g  = (1.f - zz) * nn + zz * hs[r][f];
        g_out[n * F_DIM + f] = g;
        float inv = expf(-(float)n * (9.210340371976184f / 64.0f)); // 10000^(-2n/F)
        float ang = (float)t * inv;
        float pe  = ((t & 1) == 0) ? sinf(ang) : cosf(ang);
        Hm[(n * T_STEPS + t) * F_DIM + f] = g + pe;
    }
}

// ---------------------------------------------------------------- qkv [N,T,3F] -> bf16 Qb/Kb [T*H, N, D], VTb [T*H, D, N]
__global__ void qkv_transpose(const float* __restrict__ qkv, short* __restrict__ Qb,
                              short* __restrict__ Kb, short* __restrict__ VTb) {
    int idx = blockIdx.x * 256 + threadIdx.x;   // over N*T*F
    if (idx >= N_NODES * TF) return;
    int n = idx / TF;
    int rem = idx % TF;
    int t = rem / F_DIM;
    int f = rem % F_DIM;
    int hh = f >> 5, d = f & 31;
    int src = (n * T_STEPS + t) * F3;
    int th = t * H_HEADS + hh;
    Qb[((size_t)th * N_NODES + n) * D_HEAD + d] = f2bf(qkv[src + f] * 0.17677669529663687f);
    Kb[((size_t)th * N_NODES + n) * D_HEAD + d] = f2bf(qkv[src + 128 + f]);
    VTb[((size_t)th * D_HEAD + d) * N_NODES + n] = f2bf(qkv[src + 256 + f]);
}

// ---------------------------------------------------------------- MFMA flash attention: 1 wave per (t*H+h, 16 q-rows)
// Unnormalized softmax (scores are small: 0.05-scale weights); per-lane partial
// row sums reduced once at the end. P transposes C-layout -> A-layout via LDS.
__global__ __launch_bounds__(64) void attn_mfma(const short* __restrict__ Qb,
                                                const short* __restrict__ Kb,
                                                const short* __restrict__ VTb,
                                                float* __restrict__ ctx) {
    int th = blockIdx.x;            // t*H + h
    int t = th >> 2, hh = th & 3;
    int q0 = blockIdx.y * 16;
    int lane = threadIdx.x;
    int col  = lane & 15;           // n-col / d-col
    int quad = lane >> 4;           // 0..3
    __shared__ short Ps[16][40];    // +8 pad: b128 reads spread across banks

    // Q fragment (A-layout: row=lane&15, k=quad*8+j) — contiguous 16B
    bf16x8 qf = *(const bf16x8*)(Qb + ((size_t)(th * N_NODES + q0 + col)) * D_HEAD + quad * 8);
    const short* Kbase = Kb  + (size_t)th * (N_NODES * D_HEAD);
    const short* Vbase = VTb + (size_t)th * (D_HEAD * N_NODES);

    f32x4 o0 = {0.f, 0.f, 0.f, 0.f}, o1 = {0.f, 0.f, 0.f, 0.f};
    float lr0 = 0.f, lr1 = 0.f, lr2 = 0.f, lr3 = 0.f;
    const f32x4 zc = {0.f, 0.f, 0.f, 0.f};

    for (int mt = 0; mt < 32; ++mt) {
        int m0 = mt * 32;
        // K fragments (B-layout: n=lane&15, k=quad*8+j) — contiguous 16B
        bf16x8 k0 = *(const bf16x8*)(Kbase + (size_t)(m0 + col) * D_HEAD + quad * 8);
        bf16x8 k1 = *(const bf16x8*)(Kbase + (size_t)(m0 + 16 + col) * D_HEAD + quad * 8);
        f32x4 s0 = __builtin_amdgcn_mfma_f32_16x16x32_bf16(qf, k0, zc, 0, 0, 0);
        f32x4 s1 = __builtin_amdgcn_mfma_f32_16x16x32_bf16(qf, k1, zc, 0, 0, 0);
        float p0[4], p1[4];
#pragma unroll
        for (int r = 0; r < 4; ++r) {
            p0[r] = __expf(fminf(s0[r], 80.f));
            p1[r] = __expf(fminf(s1[r], 80.f));
        }
        lr0 += p0[0] + p1[0]; lr1 += p0[1] + p1[1];
        lr2 += p0[2] + p1[2]; lr3 += p0[3] + p1[3];
        __syncthreads();   // WAR vs previous iteration's Ps reads
#pragma unroll
        for (int r = 0; r < 4; ++r) {
            Ps[quad * 4 + r][col]      = f2bf(p0[r]);
            Ps[quad * 4 + r][col + 16] = f2bf(p1[r]);
        }
        __syncthreads();   // RAW
        bf16x8 pf = *(const bf16x8*)(&Ps[col][quad * 8]);
        // V fragments (B-layout: n=d, k=m) from d-major V^T — contiguous 16B
        bf16x8 v0 = *(const bf16x8*)(Vbase + (size_t)col * N_NODES + m0 + quad * 8);
        bf16x8 v1 = *(const bf16x8*)(Vbase + (size_t)(col + 16) * N_NODES + m0 + quad * 8);
        o0 = __builtin_amdgcn_mfma_f32_16x16x32_bf16(pf, v0, o0, 0, 0, 0);
        o1 = __builtin_amdgcn_mfma_f32_16x16x32_bf16(pf, v1, o1, 0, 0, 0);
    }
    float lr[4] = {lr0, lr1, lr2, lr3};
#pragma unroll
    for (int r = 0; r < 4; ++r) {
        float s = lr[r];
        s += __shfl_xor(s, 1); s += __shfl_xor(s, 2);
        s += __shfl_xor(s, 4); s += __shfl_xor(s, 8);
        lr[r] = 1.f / s;
    }
#pragma unroll
    for (int r = 0; r < 4; ++r) {
        int n = q0 + quad * 4 + r;
        size_t base = ((size_t)n * T_STEPS + t) * F_DIM + hh * D_HEAD;
        ctx[base + col]      = o0[r] * lr[r];
        ctx[base + 16 + col] = o1[r] * lr[r];
    }
}

// ---------------------------------------------------------------- LayerNorm over F=128, optional residual
__global__ void ln_kernel(const float* __restrict__ a, const float* __restrict__ resid,
                          const float* __restrict__ gamma, const float* __restrict__ beta,
                          float* __restrict__ out) {
    int row = blockIdx.x;
    int tid = threadIdx.x;    // 64 threads, 2 elements each
    int base = row * F_DIM;
    float x0 = a[base + tid], x1 = a[base + 64 + tid];
    if (resid) { x0 += resid[base + tid]; x1 += resid[base + 64 + tid]; }
    float s = x0 + x1;
#pragma unroll
    for (int o = 32; o > 0; o >>= 1) s += __shfl_xor(s, o);
    float mu = s * (1.f / 128.f);
    float d0 = x0 - mu, d1 = x1 - mu;
    float v = d0 * d0 + d1 * d1;
#pragma unroll
    for (int o = 32; o > 0; o >>= 1) v += __shfl_xor(v, o);
    float inv = rsqrtf(v * (1.f / 128.f) + 1e-5f);
    out[base + tid]      = d0 * inv * gamma[tid] + beta[tid];
    out[base + 64 + tid] = d1 * inv * gamma[64 + tid] + beta[64 + tid];
}

// ---------------------------------------------------------------- tiled fp32 GEMM: C[M,P] = A[M,K] @ B (+bias, relu)
template <bool TB, bool RELU>
__global__ __launch_bounds__(256) void gemm_kernel(const float* __restrict__ A,
                                                   const float* __restrict__ B,
                                                   const float* __restrict__ bias,
                                                   float* __restrict__ C,
                                                   int M, int K, int P) {
    __shared__ float As[16][65];
    __shared__ float Bs[16][65];
    int tid = threadIdx.x;
    int tx = tid & 15, ty = tid >> 4;
    int p0 = blockIdx.x * 64, row0 = blockIdx.y * 64;
    float acc[4][4] = {};
    for (int k0 = 0; k0 < K; k0 += 16) {
        {
            int m = tid & 63, kb = (tid >> 6) * 4;
            const float4 f4 = *(const float4*)(A + (size_t)(row0 + m) * K + k0 + kb);
            As[kb + 0][m] = f4.x; As[kb + 1][m] = f4.y;
            As[kb + 2][m] = f4.z; As[kb + 3][m] = f4.w;
        }
        if (TB) {
            int p = tid >> 2, kb = (tid & 3) * 4;
            const float4 f4 = *(const float4*)(B + (size_t)(p0 + p) * K + k0 + kb);
            Bs[kb + 0][p] = f4.x; Bs[kb + 1][p] = f4.y;
            Bs[kb + 2][p] = f4.z; Bs[kb + 3][p] = f4.w;
        } else {
            int p = tid & 63, kb = (tid >> 6) * 4;
#pragma unroll
            for (int j = 0; j < 4; ++j) Bs[kb + j][p] = B[(size_t)(k0 + kb + j) * P + p0 + p];
        }
        __syncthreads();
#pragma unroll
        for (int k = 0; k < 16; ++k) {
            float av[4], bv[4];
#pragma unroll
            for (int i = 0; i < 4; ++i) av[i] = As[k][ty * 4 + i];
#pragma unroll
            for (int j = 0; j < 4; ++j) bv[j] = Bs[k][tx * 4 + j];
#pragma unroll
            for (int i = 0; i < 4; ++i)
#pragma unroll
                for (int j = 0; j < 4; ++j) acc[i][j] += av[i] * bv[j];
        }
        __syncthreads();
    }
#pragma unroll
    for (int i = 0; i < 4; ++i) {
        int row = row0 + ty * 4 + i;
#pragma unroll
        for (int j = 0; j < 4; ++j) {
            int col = p0 + tx * 4 + j;
            float v = acc[i][j] + (bias ? bias[col] : 0.f);
            if (RELU) v = fmaxf(v, 0.f);
            C[(size_t)row * P + col] = v;
        }
    }
}

// ---------------------------------------------------------------- launch
extern "C" void kernel_launch(void* const* d_in, const int* in_sizes, int n_in,
                              void* d_out, int out_size, void* d_ws, size_t ws_size,
                              hipStream_t stream) {
    const int*   A_cols     = (const int*)d_in[1];
    const float* A_vals     = (const float*)d_in[2];
    const float* X          = (const float*)d_in[3];
    const float* W_gcn      = (const float*)d_in[4];
    const float* W_ih       = (const float*)d_in[5];
    const float* W_hh       = (const float*)d_in[6];
    const float* b_ih       = (const float*)d_in[7];
    const float* b_hh       = (const float*)d_in[8];
    const float* in_proj_w  = (const float*)d_in[9];
    const float* in_proj_b  = (const float*)d_in[10];
    const float* out_proj_w = (const float*)d_in[11];
    const float* out_proj_b = (const float*)d_in[12];
    const float* ln1_g = (const float*)d_in[13];
    const float* ln1_b = (const float*)d_in[14];
    const float* ln2_g = (const float*)d_in[15];
    const float* ln2_b = (const float*)d_in[16];
    const float* lnf_g = (const float*)d_in[17];
    const float* lnf_b = (const float*)d_in[18];
    const float* ff1_w = (const float*)d_in[19];
    const float* ff1_b = (const float*)d_in[20];
    const float* ff2_w = (const float*)d_in[21];
    const float* ff2_b = (const float*)d_in[22];
    const float* fc1_w = (const float*)d_in[23];
    const float* fc1_b = (const float*)d_in[24];
    const float* fc2_w = (const float*)d_in[25];
    const float* fc2_b = (const float*)d_in[26];
    const float* fc3_w = (const float*)d_in[27];
    const float* fc3_b = (const float*)d_in[28];
    float* out = (float*)d_out;
    float* ws  = (float*)d_ws;

    const size_t o_Hm = 0;                       // [N,T,F]  4,194,304
    const size_t o_A  = o_Hm + 4194304;          // X_s -> ctx -> x1 -> enc
    const size_t o_B  = o_A + 4194304;           // X_tilde -> attn_out -> ff_out
    const size_t o_C  = o_B + 4194304;           // GI -> qkv -> ff_hid(16.8M, spills into o_D)
    const size_t o_D  = o_C + 12582912;          // Qb/Kb/VTb bf16 (25MB of the 50MB region)
    const size_t o_WT = o_D + 12582912;          // W_hhT 49,152
    const size_t o_h  = o_WT + 49152;
    const size_t o_g  = o_h + 131072;
    const size_t o_h1 = o_g + 131072;
    const size_t o_h2 = o_h1 + 524288;

    float* Hm   = ws + o_Hm;
    float* bufA = ws + o_A;
    float* bufB = ws + o_B;
    float* bufC = ws + o_C;
    short* Qb   = (short*)(ws + o_D);
    short* Kb   = Qb + 4194304;
    short* VTb  = Kb + 4194304;
    float* WhhT = ws + o_WT;
    float* hbuf = ws + o_h;
    float* gbuf = ws + o_g;
    float* h1   = ws + o_h1;
    float* h2   = ws + o_h2;

    // 1. X_s = A_hat @ X  [N, T*F] -> bufA
    spmm_wide<<<dim3(16, 1024), 256, 0, stream>>>(A_cols, A_vals, X, bufA);
    // 2. X_tilde = relu(X_s @ W_gcn) -> bufB  (view [NT,F])
    gemm_kernel<false, true><<<dim3(2, 512), 256, 0, stream>>>(bufA, W_gcn, nullptr, bufB, NT, F_DIM, F_DIM);
    // 3. GI = X_tilde @ W_ih^T + b_ih -> bufC [NT, 384]
    gemm_kernel<true, false><<<dim3(6, 512), 256, 0, stream>>>(bufB, W_ih, b_ih, bufC, NT, F_DIM, F3);
    // 4. W_hh transpose
    transpose_whh<<<192, 256, 0, stream>>>(W_hh, WhhT);
    // 5. h0 = 0
    zero_kernel<<<512, 256, 0, stream>>>(hbuf, 131072);
    // 6. sequential scan
    for (int t = 0; t < T_STEPS; ++t) {
        gru_step<<<64, 256, 0, stream>>>(bufC, hbuf, WhhT, b_hh, gbuf, Hm, t);
        spmm_gcn<<<1024, 128, 0, stream>>>(A_cols, A_vals, gbuf, W_gcn, hbuf);
    }
    // 7. qkv = Hm @ in_proj_w^T + b -> bufC [NT, 384]
    gemm_kernel<true, false><<<dim3(6, 512), 256, 0, stream>>>(Hm, in_proj_w, in_proj_b, bufC, NT, F_DIM, F3);
    // 8. bf16 transpose to [T*H, N, D] (+ scale q), V d-major
    qkv_transpose<<<16384, 256, 0, stream>>>(bufC, Qb, Kb, VTb);
    // 9. MFMA attention -> ctx (bufA)
    attn_mfma<<<dim3(128, 64), 64, 0, stream>>>(Qb, Kb, VTb, bufA);
    // 10. attn_out = ctx @ out_proj_w^T + b -> bufB
    gemm_kernel<true, false><<<dim3(2, 512), 256, 0, stream>>>(bufA, out_proj_w, out_proj_b, bufB, NT, F_DIM, F_DIM);
    // 11. x1 = LN(Hm + attn_out) -> bufA
    ln_kernel<<<NT, 64, 0, stream>>>(Hm, bufB, ln1_g, ln1_b, bufA);
    // 12. ff_hid = relu(x1 @ ff1_w^T + b) -> bufC
    gemm_kernel<true, true><<<dim3(8, 512), 256, 0, stream>>>(bufA, ff1_w, ff1_b, bufC, NT, F_DIM, HID);
    // 13. ff_out = ff_hid @ ff2_w^T + b -> bufB
    gemm_kernel<true, false><<<dim3(2, 512), 256, 0, stream>>>(bufC, ff2_w, ff2_b, bufB, NT, HID, F_DIM);
    // 14. x2 = LN(x1 + ff_out) -> Hm
    ln_kernel<<<NT, 64, 0, stream>>>(bufA, bufB, ln2_g, ln2_b, Hm);
    // 15. enc = LN(x2) -> bufA
    ln_kernel<<<NT, 64, 0, stream>>>(Hm, nullptr, lnf_g, lnf_b, bufA);
    // 16. h1 = relu(enc_flat @ fc1_w^T + b)
    gemm_kernel<true, true><<<dim3(8, 16), 256, 0, stream>>>(bufA, fc1_w, fc1_b, h1, N_NODES, TF, HID);
    // 17. h2 = relu(h1 @ fc2_w^T + b)
    gemm_kernel<true, true><<<dim3(8, 16), 256, 0, stream>>>(h1, fc2_w, fc2_b, h2, N_NODES, HID, HID);
    // 18. out = h2 @ fc3_w^T + b
    gemm_kernel<true, false><<<dim3(1, 16), 256, 0, stream>>>(h2, fc3_w, fc3_b, out, N_NODES, HID, OUT_DIM);
}

// Round 3
// 1166.651 us; speedup vs baseline: 2.3665x; 1.4877x over previous
//
#include <hip/hip_runtime.h>
#include <hip/hip_bf16.h>
#include <math.h>

#define N_NODES 1024
#define T_STEPS 32
#define F_DIM   128
#define H_HEADS 4
#define D_HEAD  32
#define DEG     32
#define HID     512
#define OUT_DIM 64
#define TF      (T_STEPS * F_DIM)   // 4096
#define NT      (N_NODES * T_STEPS) // 32768
#define F3      (3 * F_DIM)         // 384

typedef __attribute__((ext_vector_type(8))) __bf16 bf16x8;
typedef __attribute__((ext_vector_type(4))) float  f32x4;

// float -> bf16 bits, round-to-nearest-even (scalar fallback)
__device__ __forceinline__ short f2bf(float x) {
    union { float f; unsigned u; } v; v.f = x;
    unsigned r = (v.u + 0x7FFFu + ((v.u >> 16) & 1u)) >> 16;
    return (short)r;
}

// ---------------------------------------------------------------- utilities
__global__ void zero_kernel(float* p, int n) {
    int i = blockIdx.x * 256 + threadIdx.x;
    if (i < n) p[i] = 0.f;
}

template <bool RELU>
__global__ void bias_act(float* __restrict__ C, const float* __restrict__ bias,
                         int P, int total) {
    int i = blockIdx.x * 256 + threadIdx.x;
    if (i < total) {
        float v = C[i] + bias[i & (P - 1)];   // P is a power of two here
        if (RELU) v = fmaxf(v, 0.f);
        C[i] = v;
    }
}

// transpose W_hh [384,128] -> W_hhT [128,384]
__global__ void transpose_whh(const float* __restrict__ W, float* __restrict__ WT) {
    int idx = blockIdx.x * 256 + threadIdx.x;
    if (idx < F3 * F_DIM) {
        int j = idx / F_DIM;
        int k = idx % F_DIM;
        WT[k * F3 + j] = W[idx];
    }
}

// ---------------------------------------------------------------- SpMM (wide): Y[n, :] = sum_e vals * X[cols[e], :]
__global__ void spmm_wide(const int* __restrict__ cols, const float* __restrict__ vals,
                          const float* __restrict__ X, float* __restrict__ Y) {
    int n = blockIdx.y;
    int c = blockIdx.x * 256 + threadIdx.x;
    const int*   ce = cols + n * DEG;
    const float* ve = vals + n * DEG;
    float acc = 0.f;
#pragma unroll
    for (int e = 0; e < DEG; ++e) acc += ve[e] * X[ce[e] * TF + c];
    Y[n * TF + c] = acc;
}

// ---------------------------------------------------------------- fused SpMM(F) + @W_gcn + relu
__global__ void spmm_gcn(const int* __restrict__ cols, const float* __restrict__ vals,
                         const float* __restrict__ g_in, const float* __restrict__ Wg,
                         float* __restrict__ h_out) {
    __shared__ float sp[F_DIM];
    int n = blockIdx.x, tid = threadIdx.x;   // 128 threads
    const int*   ce = cols + n * DEG;
    const float* ve = vals + n * DEG;
    float acc = 0.f;
#pragma unroll
    for (int e = 0; e < DEG; ++e) acc += ve[e] * g_in[ce[e] * F_DIM + tid];
    sp[tid] = acc;
    __syncthreads();
    float o = 0.f;
    for (int k = 0; k < F_DIM; ++k) o += sp[k] * Wg[k * F_DIM + tid];
    h_out[n * F_DIM + tid] = fmaxf(o, 0.f);
}

// ---------------------------------------------------------------- GRU step
__global__ __launch_bounds__(256) void gru_step(const float* __restrict__ GI,
                                                const float* __restrict__ h_in,
                                                const float* __restrict__ WhhT,
                                                const float* __restrict__ b_hh,
                                                float* __restrict__ g_out,
                                                float* __restrict__ Hm, int t) {
    __shared__ float hs[16][F_DIM];
    int tid  = threadIdx.x;
    int row0 = blockIdx.x * 16;
    for (int idx = tid; idx < 16 * F_DIM; idx += 256) {
        int j = idx >> 7, f2 = idx & 127;
        hs[j][f2] = h_in[(row0 + j) * F_DIM + f2];
    }
    __syncthreads();
    int f  = tid & 127;
    int rg = tid >> 7;
    float hr[8], hz[8], hn[8];
#pragma unroll
    for (int i = 0; i < 8; ++i) { hr[i] = 0.f; hz[i] = 0.f; hn[i] = 0.f; }
    for (int k = 0; k < F_DIM; ++k) {
        float wr = WhhT[k * F3 + f];
        float wz = WhhT[k * F3 + 128 + f];
        float wn = WhhT[k * F3 + 256 + f];
#pragma unroll
        for (int i = 0; i < 8; ++i) {
            float hv = hs[rg * 8 + i][k];
            hr[i] += hv * wr; hz[i] += hv * wz; hn[i] += hv * wn;
        }
    }
    float br = b_hh[f], bz = b_hh[128 + f], bn = b_hh[256 + f];
#pragma unroll
    for (int i = 0; i < 8; ++i) {
        int r = rg * 8 + i;
        int n = row0 + r;
        int gib = (n * T_STEPS + t) * F3;
        float ir  = GI[gib + f];
        float iz  = GI[gib + 128 + f];
        float inn = GI[gib + 256 + f];
        float rr = 1.f / (1.f + expf(-(ir + hr[i] + br)));
        float zz = 1.f / (1.f + expf(-(iz + hz[i] + bz)));
        float nn = tanhf(inn + rr * (hn[i] + bn));
        float g  = (1.f - zz) * nn + zz * hs[r][f];
        g_out[n * F_DIM + f] = g;
        float inv = expf(-(float)n * (9.210340371976184f / 64.0f)); // 10000^(-2n/F)
        float ang = (float)t * inv;
        float pe  = ((t & 1) == 0) ? sinf(ang) : cosf(ang);
        Hm[(n * T_STEPS + t) * F_DIM + f] = g + pe;
    }
}

// ---------------------------------------------------------------- qkv [N,T,3F] -> bf16 Qb/Kb [T*H, N, D], VTb [T*H, D, N]
__global__ void qkv_transpose(const float* __restrict__ qkv, short* __restrict__ Qb,
                              short* __restrict__ Kb, short* __restrict__ VTb) {
    int idx = blockIdx.x * 256 + threadIdx.x;
    if (idx >= N_NODES * TF) return;
    int n = idx / TF;
    int rem = idx % TF;
    int t = rem / F_DIM;
    int f = rem % F_DIM;
    int hh = f >> 5, d = f & 31;
    int src = (n * T_STEPS + t) * F3;
    int th = t * H_HEADS + hh;
    Qb[((size_t)th * N_NODES + n) * D_HEAD + d] = f2bf(qkv[src + f] * 0.17677669529663687f);
    Kb[((size_t)th * N_NODES + n) * D_HEAD + d] = f2bf(qkv[src + 128 + f]);
    VTb[((size_t)th * D_HEAD + d) * N_NODES + n] = f2bf(qkv[src + 256 + f]);
}

// ---------------------------------------------------------------- MFMA flash attention: 1 wave per (t*H+h, 16 q-rows)
__global__ __launch_bounds__(64) void attn_mfma(const short* __restrict__ Qb,
                                                const short* __restrict__ Kb,
                                                const short* __restrict__ VTb,
                                                float* __restrict__ ctx) {
    int th = blockIdx.x;
    int t = th >> 2, hh = th & 3;
    int q0 = blockIdx.y * 16;
    int lane = threadIdx.x;
    int col  = lane & 15;
    int quad = lane >> 4;
    __shared__ short Ps[16][40];

    bf16x8 qf = *(const bf16x8*)(Qb + ((size_t)(th * N_NODES + q0 + col)) * D_HEAD + quad * 8);
    const short* Kbase = Kb  + (size_t)th * (N_NODES * D_HEAD);
    const short* Vbase = VTb + (size_t)th * (D_HEAD * N_NODES);

    f32x4 o0 = {0.f, 0.f, 0.f, 0.f}, o1 = {0.f, 0.f, 0.f, 0.f};
    float lr0 = 0.f, lr1 = 0.f, lr2 = 0.f, lr3 = 0.f;
    const f32x4 zc = {0.f, 0.f, 0.f, 0.f};

    for (int mt = 0; mt < 32; ++mt) {
        int m0 = mt * 32;
        bf16x8 k0 = *(const bf16x8*)(Kbase + (size_t)(m0 + col) * D_HEAD + quad * 8);
        bf16x8 k1 = *(const bf16x8*)(Kbase + (size_t)(m0 + 16 + col) * D_HEAD + quad * 8);
        f32x4 s0 = __builtin_amdgcn_mfma_f32_16x16x32_bf16(qf, k0, zc, 0, 0, 0);
        f32x4 s1 = __builtin_amdgcn_mfma_f32_16x16x32_bf16(qf, k1, zc, 0, 0, 0);
        float p0[4], p1[4];
#pragma unroll
        for (int r = 0; r < 4; ++r) {
            p0[r] = __expf(fminf(s0[r], 80.f));
            p1[r] = __expf(fminf(s1[r], 80.f));
        }
        lr0 += p0[0] + p1[0]; lr1 += p0[1] + p1[1];
        lr2 += p0[2] + p1[2]; lr3 += p0[3] + p1[3];
        __syncthreads();
#pragma unroll
        for (int r = 0; r < 4; ++r) {
            Ps[quad * 4 + r][col]      = f2bf(p0[r]);
            Ps[quad * 4 + r][col + 16] = f2bf(p1[r]);
        }
        __syncthreads();
        bf16x8 pf = *(const bf16x8*)(&Ps[col][quad * 8]);
        bf16x8 v0 = *(const bf16x8*)(Vbase + (size_t)col * N_NODES + m0 + quad * 8);
        bf16x8 v1 = *(const bf16x8*)(Vbase + (size_t)(col + 16) * N_NODES + m0 + quad * 8);
        o0 = __builtin_amdgcn_mfma_f32_16x16x32_bf16(pf, v0, o0, 0, 0, 0);
        o1 = __builtin_amdgcn_mfma_f32_16x16x32_bf16(pf, v1, o1, 0, 0, 0);
    }
    float lr[4] = {lr0, lr1, lr2, lr3};
#pragma unroll
    for (int r = 0; r < 4; ++r) {
        float s = lr[r];
        s += __shfl_xor(s, 1); s += __shfl_xor(s, 2);
        s += __shfl_xor(s, 4); s += __shfl_xor(s, 8);
        lr[r] = 1.f / s;
    }
#pragma unroll
    for (int r = 0; r < 4; ++r) {
        int n = q0 + quad * 4 + r;
        size_t base = ((size_t)n * T_STEPS + t) * F_DIM + hh * D_HEAD;
        ctx[base + col]      = o0[r] * lr[r];
        ctx[base + 16 + col] = o1[r] * lr[r];
    }
}

// ---------------------------------------------------------------- LayerNorm over F=128, optional residual
__global__ void ln_kernel(const float* __restrict__ a, const float* __restrict__ resid,
                          const float* __restrict__ gamma, const float* __restrict__ beta,
                          float* __restrict__ out) {
    int row = blockIdx.x;
    int tid = threadIdx.x;
    int base = row * F_DIM;
    float x0 = a[base + tid], x1 = a[base + 64 + tid];
    if (resid) { x0 += resid[base + tid]; x1 += resid[base + 64 + tid]; }
    float s = x0 + x1;
#pragma unroll
    for (int o = 32; o > 0; o >>= 1) s += __shfl_xor(s, o);
    float mu = s * (1.f / 128.f);
    float d0 = x0 - mu, d1 = x1 - mu;
    float v = d0 * d0 + d1 * d1;
#pragma unroll
    for (int o = 32; o > 0; o >>= 1) v += __shfl_xor(v, o);
    float inv = rsqrtf(v * (1.f / 128.f) + 1e-5f);
    out[base + tid]      = d0 * inv * gamma[tid] + beta[tid];
    out[base + 64 + tid] = d1 * inv * gamma[64 + tid] + beta[64 + tid];
}

// ---------------------------------------------------------------- bf16 MFMA GEMM: C[M,P] = A[M,K] @ B (+bias,relu)
// TB ? B is [P,K] : B is [K,P].  64x64 tile, 4 waves, fp32->bf16 staging.
// SPLITK: grid.z slices K into Kc chunks, atomicAdd into pre-zeroed C (no bias/relu).
template <bool TB, bool RELU, bool SPLITK>
__global__ __launch_bounds__(256) void mfma_gemm(const float* __restrict__ A,
                                                 const float* __restrict__ B,
                                                 const float* __restrict__ bias,
                                                 float* __restrict__ C,
                                                 int M, int K, int P, int Kc) {
    __shared__ short As[64][40];
    __shared__ short Bs[64][40];
    int tid = threadIdx.x;
    int p0 = blockIdx.x * 64, row0 = blockIdx.y * 64;
    int k_begin = SPLITK ? blockIdx.z * Kc : 0;
    int k_end   = SPLITK ? k_begin + Kc : K;
    int lane = tid & 63, w = tid >> 6, col = lane & 15, quad = lane >> 4;
    f32x4 acc[4];
#pragma unroll
    for (int j = 0; j < 4; ++j) acc[j] = (f32x4){0.f, 0.f, 0.f, 0.f};

    for (int k0 = k_begin; k0 < k_end; k0 += 32) {
        // stage A tile 64x32 (fp32 -> bf16)
#pragma unroll
        for (int i = 0; i < 2; ++i) {
            int idx = tid * 2 + i;
            int r = idx >> 3, c4 = (idx & 7) << 2;
            const float4 f4 = *(const float4*)(A + (size_t)(row0 + r) * K + k0 + c4);
            union { __hip_bfloat162 h2[2]; short4 s4; } u;
            u.h2[0] = __float22bfloat162_rn(make_float2(f4.x, f4.y));
            u.h2[1] = __float22bfloat162_rn(make_float2(f4.z, f4.w));
            *(short4*)&As[r][c4] = u.s4;
        }
        if (TB) {
#pragma unroll
            for (int i = 0; i < 2; ++i) {
                int idx = tid * 2 + i;
                int r = idx >> 3, c4 = (idx & 7) << 2;
                const float4 f4 = *(const float4*)(B + (size_t)(p0 + r) * K + k0 + c4);
                union { __hip_bfloat162 h2[2]; short4 s4; } u;
                u.h2[0] = __float22bfloat162_rn(make_float2(f4.x, f4.y));
                u.h2[1] = __float22bfloat162_rn(make_float2(f4.z, f4.w));
                *(short4*)&Bs[r][c4] = u.s4;
            }
        } else {
#pragma unroll
            for (int i = 0; i < 2; ++i) {
                int idx = tid * 2 + i;
                int kk = idx >> 4, c4 = (idx & 15) << 2;
                const float4 f4 = *(const float4*)(B + (size_t)(k0 + kk) * P + p0 + c4);
                Bs[c4 + 0][kk] = f2bf(f4.x);
                Bs[c4 + 1][kk] = f2bf(f4.y);
                Bs[c4 + 2][kk] = f2bf(f4.z);
                Bs[c4 + 3][kk] = f2bf(f4.w);
            }
        }
        __syncthreads();
        bf16x8 af = *(const bf16x8*)&As[w * 16 + col][quad * 8];
#pragma unroll
        for (int j = 0; j < 4; ++j) {
            bf16x8 bv = *(const bf16x8*)&Bs[j * 16 + col][quad * 8];
            acc[j] = __builtin_amdgcn_mfma_f32_16x16x32_bf16(af, bv, acc[j], 0, 0, 0);
        }
        __syncthreads();
    }
#pragma unroll
    for (int j = 0; j < 4; ++j) {
        int cg = p0 + j * 16 + col;
        float bvv = (!SPLITK && bias) ? bias[cg] : 0.f;
#pragma unroll
        for (int r = 0; r < 4; ++r) {
            int rg = row0 + w * 16 + quad * 4 + r;
            if (SPLITK) {
                atomicAdd(&C[(size_t)rg * P + cg], acc[j][r]);
            } else {
                float v = acc[j][r] + bvv;
                if (RELU) v = fmaxf(v, 0.f);
                C[(size_t)rg * P + cg] = v;
            }
        }
    }
}

// ---------------------------------------------------------------- launch
extern "C" void kernel_launch(void* const* d_in, const int* in_sizes, int n_in,
                              void* d_out, int out_size, void* d_ws, size_t ws_size,
                              hipStream_t stream) {
    const int*   A_cols     = (const int*)d_in[1];
    const float* A_vals     = (const float*)d_in[2];
    const float* X          = (const float*)d_in[3];
    const float* W_gcn      = (const float*)d_in[4];
    const float* W_ih       = (const float*)d_in[5];
    const float* W_hh       = (const float*)d_in[6];
    const float* b_ih       = (const float*)d_in[7];
    const float* b_hh       = (const float*)d_in[8];
    const float* in_proj_w  = (const float*)d_in[9];
    const float* in_proj_b  = (const float*)d_in[10];
    const float* out_proj_w = (const float*)d_in[11];
    const float* out_proj_b = (const float*)d_in[12];
    const float* ln1_g = (const float*)d_in[13];
    const float* ln1_b = (const float*)d_in[14];
    const float* ln2_g = (const float*)d_in[15];
    const float* ln2_b = (const float*)d_in[16];
    const float* lnf_g = (const float*)d_in[17];
    const float* lnf_b = (const float*)d_in[18];
    const float* ff1_w = (const float*)d_in[19];
    const float* ff1_b = (const float*)d_in[20];
    const float* ff2_w = (const float*)d_in[21];
    const float* ff2_b = (const float*)d_in[22];
    const float* fc1_w = (const float*)d_in[23];
    const float* fc1_b = (const float*)d_in[24];
    const float* fc2_w = (const float*)d_in[25];
    const float* fc2_b = (const float*)d_in[26];
    const float* fc3_w = (const float*)d_in[27];
    const float* fc3_b = (const float*)d_in[28];
    float* out = (float*)d_out;
    float* ws  = (float*)d_ws;

    const size_t o_Hm = 0;
    const size_t o_A  = o_Hm + 4194304;
    const size_t o_B  = o_A + 4194304;
    const size_t o_C  = o_B + 4194304;           // GI -> qkv -> ff_hid (spills into o_D)
    const size_t o_D  = o_C + 12582912;          // Qb/Kb/VTb bf16
    const size_t o_WT = o_D + 12582912;
    const size_t o_h  = o_WT + 49152;
    const size_t o_g  = o_h + 131072;
    const size_t o_h1 = o_g + 131072;
    const size_t o_h2 = o_h1 + 524288;

    float* Hm   = ws + o_Hm;
    float* bufA = ws + o_A;
    float* bufB = ws + o_B;
    float* bufC = ws + o_C;
    short* Qb   = (short*)(ws + o_D);
    short* Kb   = Qb + 4194304;
    short* VTb  = Kb + 4194304;
    float* WhhT = ws + o_WT;
    float* hbuf = ws + o_h;
    float* gbuf = ws + o_g;
    float* h1   = ws + o_h1;
    float* h2   = ws + o_h2;

    // 1. X_s = A_hat @ X -> bufA
    spmm_wide<<<dim3(16, 1024), 256, 0, stream>>>(A_cols, A_vals, X, bufA);
    // 2. X_tilde = relu(X_s @ W_gcn) -> bufB
    mfma_gemm<false, true, false><<<dim3(2, 512), 256, 0, stream>>>(bufA, W_gcn, nullptr, bufB, NT, F_DIM, F_DIM, 0);
    // 3. GI = X_tilde @ W_ih^T + b_ih -> bufC
    mfma_gemm<true, false, false><<<dim3(6, 512), 256, 0, stream>>>(bufB, W_ih, b_ih, bufC, NT, F_DIM, F3, 0);
    // 4. W_hh transpose
    transpose_whh<<<192, 256, 0, stream>>>(W_hh, WhhT);
    // 5. h0 = 0
    zero_kernel<<<512, 256, 0, stream>>>(hbuf, 131072);
    // 6. sequential scan
    for (int t = 0; t < T_STEPS; ++t) {
        gru_step<<<64, 256, 0, stream>>>(bufC, hbuf, WhhT, b_hh, gbuf, Hm, t);
        spmm_gcn<<<1024, 128, 0, stream>>>(A_cols, A_vals, gbuf, W_gcn, hbuf);
    }
    // 7. qkv = Hm @ in_proj_w^T + b -> bufC
    mfma_gemm<true, false, false><<<dim3(6, 512), 256, 0, stream>>>(Hm, in_proj_w, in_proj_b, bufC, NT, F_DIM, F3, 0);
    // 8. bf16 transpose (+ scale q), V d-major
    qkv_transpose<<<16384, 256, 0, stream>>>(bufC, Qb, Kb, VTb);
    // 9. MFMA attention -> ctx (bufA)
    attn_mfma<<<dim3(128, 64), 64, 0, stream>>>(Qb, Kb, VTb, bufA);
    // 10. attn_out = ctx @ out_proj_w^T + b -> bufB
    mfma_gemm<true, false, false><<<dim3(2, 512), 256, 0, stream>>>(bufA, out_proj_w, out_proj_b, bufB, NT, F_DIM, F_DIM, 0);
    // 11. x1 = LN(Hm + attn_out) -> bufA
    ln_kernel<<<NT, 64, 0, stream>>>(Hm, bufB, ln1_g, ln1_b, bufA);
    // 12. ff_hid = relu(x1 @ ff1_w^T + b) -> bufC
    mfma_gemm<true, true, false><<<dim3(8, 512), 256, 0, stream>>>(bufA, ff1_w, ff1_b, bufC, NT, F_DIM, HID, 0);
    // 13. ff_out = ff_hid @ ff2_w^T + b -> bufB
    mfma_gemm<true, false, false><<<dim3(2, 512), 256, 0, stream>>>(bufC, ff2_w, ff2_b, bufB, NT, HID, F_DIM, 0);
    // 14. x2 = LN(x1 + ff_out) -> Hm
    ln_kernel<<<NT, 64, 0, stream>>>(bufA, bufB, ln2_g, ln2_b, Hm);
    // 15. enc = LN(x2) -> bufA
    ln_kernel<<<NT, 64, 0, stream>>>(Hm, nullptr, lnf_g, lnf_b, bufA);
    // 16. h1 = relu(enc_flat @ fc1_w^T + b)  — split-K=4
    zero_kernel<<<2048, 256, 0, stream>>>(h1, 524288);
    mfma_gemm<true, false, true><<<dim3(8, 16, 4), 256, 0, stream>>>(bufA, fc1_w, nullptr, h1, N_NODES, TF, HID, 1024);
    bias_act<true><<<2048, 256, 0, stream>>>(h1, fc1_b, HID, 524288);
    // 17. h2 = relu(h1 @ fc2_w^T + b) — split-K=4
    zero_kernel<<<2048, 256, 0, stream>>>(h2, 524288);
    mfma_gemm<true, false, true><<<dim3(8, 16, 4), 256, 0, stream>>>(h1, fc2_w, nullptr, h2, N_NODES, HID, HID, 128);
    bias_act<true><<<2048, 256, 0, stream>>>(h2, fc2_b, HID, 524288);
    // 18. out = h2 @ fc3_w^T + b — split-K=8
    zero_kernel<<<256, 256, 0, stream>>>(out, 65536);
    mfma_gemm<true, false, true><<<dim3(1, 16, 8), 256, 0, stream>>>(h2, fc3_w, nullptr, out, N_NODES, HID, OUT_DIM, 64);
    bias_act<false><<<256, 256, 0, stream>>>(out, fc3_b, OUT_DIM, 65536);
}